// Round 1
// 413.507 us; speedup vs baseline: 1.0391x; 1.0391x over previous
//
#include <hip/hip_runtime.h>
#include <hip/hip_bf16.h>
#include <math.h>

#define B_   2
#define S_   2048
#define HID_ 2048
#define H_   16
#define HK_  4
#define D_   128
#define NH_  24          // H + 2*HK
#define QKVN 3072        // NH_ * D_
#define R_   64

typedef __attribute__((ext_vector_type(8))) short sh8;       // 8 bf16 MFMA frag
typedef __attribute__((ext_vector_type(4))) short sh4;       // 4 bf16 (b64 store)
typedef __attribute__((ext_vector_type(2))) short sh2;
typedef __attribute__((ext_vector_type(8))) _Float16 h8;     // 8 fp16 MFMA frag
typedef __attribute__((ext_vector_type(2))) _Float16 h2;
typedef __attribute__((ext_vector_type(4))) float f4;        // MFMA accumulator

__device__ __forceinline__ short bf16_of(float x) {
    __hip_bfloat16 h = __float2bfloat16(x);
    return *reinterpret_cast<short*>(&h);
}
__device__ __forceinline__ float f_of_bf16(short s) {
    __hip_bfloat16 h = *reinterpret_cast<__hip_bfloat16*>(&s);
    return __bfloat162float(h);
}

// async global->LDS, 16B per lane; LDS dest = wave-uniform base + lane*16
#define GLOAD16(gp, lp) __builtin_amdgcn_global_load_lds(                      \
    (const __attribute__((address_space(1))) void*)(gp),                       \
    (__attribute__((address_space(3))) void*)(lp), 16, 0, 0)

// ---------------------------------------------------------------------------
// fp32 -> fp16 conversion, 8 elems/thread. n8 = n/8.
// ---------------------------------------------------------------------------
__global__ __launch_bounds__(256) void cvt_f16(
    const float* __restrict__ src, _Float16* __restrict__ dst, int n8)
{
    int i = blockIdx.x * 256 + threadIdx.x;
    if (i < n8) {
        float4 a = ((const float4*)src)[i * 2];
        float4 b = ((const float4*)src)[i * 2 + 1];
        h8 h;
        h[0] = (_Float16)a.x; h[1] = (_Float16)a.y;
        h[2] = (_Float16)a.z; h[3] = (_Float16)a.w;
        h[4] = (_Float16)b.x; h[5] = (_Float16)b.y;
        h[6] = (_Float16)b.z; h[7] = (_Float16)b.w;
        ((h8*)dst)[i] = h;
    }
}

// ---------------------------------------------------------------------------
// fp16 MFMA GEMM: C[M][N] = A[M][K] * B[N][K]^T, fp32 accumulate.
// 128x128 tile, BK=64, 4 waves (2x2), wave tile 64x64.
// Staging via global_load_lds width=16 (m97 2-barrier structure), linear LDS
// with both-sides XOR chunk swizzle: LDS[R][c] holds global chunk c^(R&7),
// reader fetches chunk g at LDS col (g^(R&7))*8  -> conflict-free ds_read_b128.
// ---------------------------------------------------------------------------
template<bool F16OUT>
__global__ __launch_bounds__(256) void gemm_f16(
    const _Float16* __restrict__ A, const _Float16* __restrict__ Bm,
    void* __restrict__ Cv, int M, int N, int K)
{
    __shared__ _Float16 Ast[128][64];   // linear: global_load_lds dest
    __shared__ _Float16 Bst[128][64];

    const int tid = threadIdx.x;
    const int wave = tid >> 6, lane = tid & 63;
    const int l15 = lane & 15, l4 = lane >> 4;
    const int m0 = blockIdx.y * 128, n0 = blockIdx.x * 128;
    const int wm = (wave >> 1) * 64, wn = (wave & 1) * 64;

    f4 acc[16];
#pragma unroll
    for (int t = 0; t < 16; ++t) acc[t] = (f4){0.f, 0.f, 0.f, 0.f};

    const int srow = lane >> 3;                    // row within 8-row chunk
    const int scol = ((lane & 7) ^ srow) * 8;      // inverse-swizzled source col
    const int sw   = l15 & 7;                      // read-side row swizzle key

    for (int k0 = 0; k0 < K; k0 += 64) {
        __syncthreads();   // prev iter's ds_reads drained (lgkmcnt before barrier)
#pragma unroll
        for (int t = 0; t < 4; ++t) {
            const int chunk = wave * 4 + t;        // 0..15: 8 rows each
            const int grow  = chunk * 8 + srow;
            GLOAD16(A  + (size_t)(m0 + grow) * K + k0 + scol, &Ast[chunk * 8][0]);
            GLOAD16(Bm + (size_t)(n0 + grow) * K + k0 + scol, &Bst[chunk * 8][0]);
        }
        __syncthreads();   // compiler emits vmcnt(0) drain: LDS tile ready

#pragma unroll
        for (int j = 0; j < 2; ++j) {
            h8 ahf[4], bhf[4];
#pragma unroll
            for (int i = 0; i < 4; ++i) {
                ahf[i] = *(const h8*)&Ast[wm + i * 16 + l15][((j * 4 + l4) ^ sw) * 8];
                bhf[i] = *(const h8*)&Bst[wn + i * 16 + l15][((j * 4 + l4) ^ sw) * 8];
            }
            __builtin_amdgcn_s_setprio(1);
#pragma unroll
            for (int i = 0; i < 4; ++i)
#pragma unroll
                for (int jj = 0; jj < 4; ++jj)
                    acc[i * 4 + jj] = __builtin_amdgcn_mfma_f32_16x16x32_f16(
                        ahf[i], bhf[jj], acc[i * 4 + jj], 0, 0, 0);
            __builtin_amdgcn_s_setprio(0);
        }
    }

#pragma unroll
    for (int i = 0; i < 4; ++i)
#pragma unroll
        for (int jj = 0; jj < 4; ++jj)
#pragma unroll
            for (int r = 0; r < 4; ++r) {
                int row = m0 + wm + i * 16 + l4 * 4 + r;
                int col = n0 + wn + jj * 16 + l15;
                if (F16OUT)
                    ((_Float16*)Cv)[(size_t)row * N + col] = (_Float16)acc[i * 4 + jj][r];
                else
                    ((float*)Cv)[(size_t)row * N + col] = acc[i * 4 + jj][r];
            }
}

// ---------------------------------------------------------------------------
// Fused RMSNorm (q,k heads) + partial RoPE, one wave per head-row.
// 2 elems/lane, shuffle reduce, no LDS, no barriers.
//   h in [0,16)  -> Q fp32 (B,H,S,D)
//   h in [16,20) -> Khi/Klo bf16-split (B,HK,S,D)
// ---------------------------------------------------------------------------
__global__ __launch_bounds__(256) void norm_rope(
    const _Float16* __restrict__ qkv,
    const float* __restrict__ cosT, const float* __restrict__ sinT,
    const float* __restrict__ qw, const float* __restrict__ kw,
    float* __restrict__ Q, short* __restrict__ Khi_g, short* __restrict__ Klo_g)
{
    const int tid = threadIdx.x;
    const int wave = tid >> 6, lane = tid & 63;
    const int h = blockIdx.x * 4 + wave;    // 0..19
    const int s = blockIdx.y, b = blockIdx.z;
    const size_t tok = (size_t)b * S_ + s;

    h2 xv = *(const h2*)(qkv + (tok * NH_ + h) * D_ + 2 * lane);
    float x0 = (float)xv[0], x1 = (float)xv[1];
    float ss = x0 * x0 + x1 * x1;
    ss += __shfl_xor(ss, 1);  ss += __shfl_xor(ss, 2);  ss += __shfl_xor(ss, 4);
    ss += __shfl_xor(ss, 8);  ss += __shfl_xor(ss, 16); ss += __shfl_xor(ss, 32);
    float scale = rsqrtf(ss * (1.f / 128.f) + 1e-6f);

    const float* wp = (h < 16) ? qw : kw;
    float2 wv = ((const float2*)wp)[lane];
    float y0 = x0 * scale * wv.x;
    float y1 = x1 * scale * wv.y;

    // RoPE: d<32 -> other = -y[d+32]; 32<=d<64 -> other = +y[d-32]; d>=64 pass
    float p0 = __shfl_xor(y0, 16), p1 = __shfl_xor(y1, 16);
    if (lane < 32) {
        float2 cv = ((const float2*)(cosT + tok * R_))[lane];
        float2 sv = ((const float2*)(sinT + tok * R_))[lane];
        float sgn = (lane < 16) ? -1.f : 1.f;
        y0 = y0 * cv.x + sgn * p0 * sv.x;
        y1 = y1 * cv.y + sgn * p1 * sv.y;
    }

    if (h < 16) {
        float2* qp = (float2*)(Q + (((size_t)b * H_ + h) * S_ + s) * D_);
        qp[lane] = make_float2(y0, y1);
    } else {
        size_t idx = (((size_t)b * HK_ + (h - 16)) * S_ + s) * D_ + 2 * lane;
        short h0 = bf16_of(y0), h1 = bf16_of(y1);
        *(sh2*)(Khi_g + idx) = (sh2){h0, h1};
        *(sh2*)(Klo_g + idx) = (sh2){bf16_of(y0 - f_of_bf16(h0)),
                                     bf16_of(y1 - f_of_bf16(h1))};
    }
}

// ---------------------------------------------------------------------------
// V transpose: reads V heads out of fp16 qkv, writes bf16 Vt (B*HK, D, S).
// ---------------------------------------------------------------------------
__global__ __launch_bounds__(256) void vtrans(
    const _Float16* __restrict__ qkv, short* __restrict__ Vt_g)
{
    __shared__ float Ts[64][132];
    const int tid = threadIdx.x;
    const int sb = blockIdx.x;
    const int bh = blockIdx.y;
    const int b = bh >> 2, kh = bh & 3;

#pragma unroll
    for (int t = 0; t < 4; ++t) {
        int e = (tid + 256 * t) * 8;
        int s = e >> 7, d = e & 127;
        const _Float16* p = qkv + (((size_t)(b * S_ + sb * 64 + s)) * NH_ + 20 + kh) * D_ + d;
        h8 v = *(const h8*)p;
#pragma unroll
        for (int u = 0; u < 8; ++u) Ts[s][d + u] = (float)v[u];
    }
    __syncthreads();

#pragma unroll
    for (int tt = 0; tt < 2; ++tt) {
        int dr = (tid >> 2) + 64 * tt;
        int sc = (tid & 3) * 16;
        short tmp[16];
#pragma unroll
        for (int i = 0; i < 16; ++i) tmp[i] = bf16_of(Ts[sc + i][dr]);
        short* outp = Vt_g + ((size_t)bh * D_ + dr) * S_ + sb * 64 + sc;
        *(sh8*)outp       = *(sh8*)&tmp[0];
        *(sh8*)(outp + 8) = *(sh8*)&tmp[8];
    }
}

// ---------------------------------------------------------------------------
// MFMA flash attention, fixed-max softmax (scores bounded by RMS norm:
// |s| <= sqrt(128)), Q-tile 128, KV-tile 64, register prefetch of K/V.
// QK^T computed SWAPPED (mfma(K,Q) -> S^T in acc): lane's 4 scores land on
// consecutive kv columns of one q-row, so the P-store is 8x ds_write_b64
// (was 32x scattered ds_write_b16 -> 1.36e7 bank-conflict cycles) and the
// softmax denominator reduces with 2 shfl_xor instead of 16.
// exp folded to exp2 via log2(e) in qscale. Output attn fp16.
// ---------------------------------------------------------------------------
__global__ __launch_bounds__(256, 2) void flash_mfma(
    const float* __restrict__ Q, const short* __restrict__ Khi_g,
    const short* __restrict__ Klo_g, const short* __restrict__ Vt_g,
    _Float16* __restrict__ Ao)
{
    __shared__ short Khi[64][136];   // pad 8: row stride 272B
    __shared__ short Klo[64][136];
    __shared__ short Vt[128][72];    // V^T: [d][kv]
    __shared__ short Ps[128][72];    // P: [qrow][kv]

    const int tid = threadIdx.x;
    const int wave = tid >> 6, lane = tid & 63;
    const int l15 = lane & 15, l4 = lane >> 4;
    const int qb = blockIdx.x, h = blockIdx.y, b = blockIdx.z;
    const int kh = h >> 2;

    // ---- Q fragments (hi/lo split) for both 16-row strips ----
    // 1/sqrt(128) * log2(e): scores come out in exp2 domain
    const float qscale = 0.08838834764831845f * 1.4426950408889634f;
    sh8 qh[2][4], ql[2][4];
#pragma unroll
    for (int i = 0; i < 2; ++i) {
        const float* qrow = Q + (((size_t)b * H_ + h) * S_ + qb * 128 + wave * 32 + i * 16 + l15) * D_;
#pragma unroll
        for (int j = 0; j < 4; ++j) {
            int d0 = j * 32 + l4 * 8;
#pragma unroll
            for (int jj = 0; jj < 8; ++jj) {
                float x = qrow[d0 + jj] * qscale;
                short hi = bf16_of(x);
                qh[i][j][jj] = hi;
                ql[i][j][jj] = bf16_of(x - f_of_bf16(hi));
            }
        }
    }

    f4 o[2][8];
#pragma unroll
    for (int i = 0; i < 2; ++i)
#pragma unroll
        for (int t = 0; t < 8; ++t) o[i][t] = (f4){0.f, 0.f, 0.f, 0.f};
    float l_part[2] = {0.f, 0.f};

    const size_t kvoff = ((size_t)b * HK_ + kh) * S_ * D_;
    const short* khg = Khi_g + kvoff;
    const short* klg = Klo_g + kvoff;
    const short* vtg = Vt_g + kvoff;

    int srow[4], scol[4], vrow[4], vcol[4];
#pragma unroll
    for (int t = 0; t < 4; ++t) {
        int e = (tid + 256 * t) * 8;
        srow[t] = e >> 7; scol[t] = e & 127;
        vrow[t] = e >> 6; vcol[t] = e & 63;
    }

    sh8 kh_r[4], kl_r[4], vt_r[4];
#pragma unroll
    for (int t = 0; t < 4; ++t) {
        kh_r[t] = *(const sh8*)(khg + (size_t)srow[t] * D_ + scol[t]);
        kl_r[t] = *(const sh8*)(klg + (size_t)srow[t] * D_ + scol[t]);
        vt_r[t] = *(const sh8*)(vtg + (size_t)vrow[t] * S_ + vcol[t]);
    }

    for (int kb = 0; kb < S_ / 64; ++kb) {
        __syncthreads();
#pragma unroll
        for (int t = 0; t < 4; ++t) {
            *(sh8*)&Khi[srow[t]][scol[t]] = kh_r[t];
            *(sh8*)&Klo[srow[t]][scol[t]] = kl_r[t];
            *(sh8*)&Vt[vrow[t]][vcol[t]]  = vt_r[t];
        }
        if (kb + 1 < S_ / 64) {
            int off = (kb + 1) * 64;
#pragma unroll
            for (int t = 0; t < 4; ++t) {
                kh_r[t] = *(const sh8*)(khg + (size_t)(off + srow[t]) * D_ + scol[t]);
                kl_r[t] = *(const sh8*)(klg + (size_t)(off + srow[t]) * D_ + scol[t]);
                vt_r[t] = *(const sh8*)(vtg + (size_t)vrow[t] * S_ + off + vcol[t]);
            }
        }
        __syncthreads();

        // ---- QK^T, swapped operands: acc[c][i] rows = kv, cols = q ----
        f4 acc[4][2];
#pragma unroll
        for (int c = 0; c < 4; ++c)
#pragma unroll
            for (int i = 0; i < 2; ++i) acc[c][i] = (f4){0.f, 0.f, 0.f, 0.f};
        __builtin_amdgcn_s_setprio(1);
#pragma unroll
        for (int j = 0; j < 4; ++j) {
#pragma unroll
            for (int c = 0; c < 4; ++c) {
                sh8 khf = *(const sh8*)&Khi[c * 16 + l15][j * 32 + l4 * 8];
                sh8 klf = *(const sh8*)&Klo[c * 16 + l15][j * 32 + l4 * 8];
#pragma unroll
                for (int i = 0; i < 2; ++i) {
                    acc[c][i] = __builtin_amdgcn_mfma_f32_16x16x32_bf16(khf, qh[i][j], acc[c][i], 0, 0, 0);
                    acc[c][i] = __builtin_amdgcn_mfma_f32_16x16x32_bf16(klf, qh[i][j], acc[c][i], 0, 0, 0);
                    acc[c][i] = __builtin_amdgcn_mfma_f32_16x16x32_bf16(khf, ql[i][j], acc[c][i], 0, 0, 0);
                }
            }
        }
        __builtin_amdgcn_s_setprio(0);

        // ---- exp2 + P-store: lane's 4 values = consecutive kv of one q-row
        //      -> single b64 write per (c,i). Rows wave-local, no barrier. ----
#pragma unroll
        for (int c = 0; c < 4; ++c) {
#pragma unroll
            for (int i = 0; i < 2; ++i) {
                sh4 pk;
#pragma unroll
                for (int r = 0; r < 4; ++r) {
                    float e_ = exp2f(acc[c][i][r]);
                    l_part[i] += e_;
                    pk[r] = bf16_of(e_);
                }
                *(sh4*)&Ps[wave * 32 + i * 16 + l15][c * 16 + l4 * 4] = pk;
            }
        }

        // ---- PV ----
        __builtin_amdgcn_s_setprio(1);
#pragma unroll
        for (int s2 = 0; s2 < 2; ++s2) {
            sh8 pf0 = *(const sh8*)&Ps[wave * 32 + l15][s2 * 32 + l4 * 8];
            sh8 pf1 = *(const sh8*)&Ps[wave * 32 + 16 + l15][s2 * 32 + l4 * 8];
#pragma unroll
            for (int t = 0; t < 8; ++t) {
                sh8 vf = *(const sh8*)&Vt[t * 16 + l15][s2 * 32 + l4 * 8];
                o[0][t] = __builtin_amdgcn_mfma_f32_16x16x32_bf16(pf0, vf, o[0][t], 0, 0, 0);
                o[1][t] = __builtin_amdgcn_mfma_f32_16x16x32_bf16(pf1, vf, o[1][t], 0, 0, 0);
            }
        }
        __builtin_amdgcn_s_setprio(0);
    }

    // ---- softmax denominator: lane holds partial over its kv slots for
    //      q = i*16 + l15; reduce across l4 groups, then broadcast to the
    //      o C-layout rows (q = l4*4 + r). ----
    float Linv[2];
#pragma unroll
    for (int i = 0; i < 2; ++i) {
        float l = l_part[i];
        l += __shfl_xor(l, 16);
        l += __shfl_xor(l, 32);
        Linv[i] = 1.f / l;
    }
#pragma unroll
    for (int i = 0; i < 2; ++i) {
        float inv[4];
#pragma unroll
        for (int r = 0; r < 4; ++r) inv[r] = __shfl(Linv[i], l4 * 4 + r);
#pragma unroll
        for (int t = 0; t < 8; ++t) {
#pragma unroll
            for (int r = 0; r < 4; ++r) {
                int row = qb * 128 + wave * 32 + i * 16 + l4 * 4 + r;
                Ao[((size_t)b * S_ + row) * (H_ * D_) + h * D_ + t * 16 + l15] =
                    (_Float16)(o[i][t][r] * inv[r]);
            }
        }
    }
}

// ---------------------------------------------------------------------------
extern "C" void kernel_launch(void* const* d_in, const int* in_sizes, int n_in,
                              void* d_out, int out_size, void* d_ws, size_t ws_size,
                              hipStream_t stream)
{
    const float* hidden  = (const float*)d_in[0];
    const float* cosT    = (const float*)d_in[1];
    const float* sinT    = (const float*)d_in[2];
    const float* w_qkv   = (const float*)d_in[3];
    const float* q_ln    = (const float*)d_in[4];
    const float* k_ln    = (const float*)d_in[5];
    const float* w_dense = (const float*)d_in[6];
    float* out = (float*)d_out;

    // workspace layout (bytes):
    //   qkv16    : B*S*3072 f16   = 25,165,824   [attn16 aliases first 16.8 MB]
    //   Q        : B*H*S*D fp32   = 33,554,432   [hidden16 aliases first 16.8 MB]
    //   Khi/Klo/Vt: 3 x 4,194,304 = 12,582,912   [wqkv16 aliases all 12.6 MB]
    //   wdense16 : 2048*2048 f16  =  8,388,608
    // total 79.7 MB
    char* w = (char*)d_ws;
    _Float16* qkv16 = (_Float16*)w;
    float*    Q     = (float*)(w + 25165824);
    short*    Khi   = (short*)(w + 25165824 + 33554432);
    short*    Klo   = Khi + 2097152;
    short*    Vt    = Klo + 2097152;
    _Float16* wdense16 = (_Float16*)(w + 25165824 + 33554432 + 12582912);
    _Float16* hidden16 = (_Float16*)Q;      // dead before norm_rope writes Q
    _Float16* wqkv16   = (_Float16*)Khi;    // dead before norm_rope writes K
    _Float16* attn16   = qkv16;             // qkv16 dead after vtrans

    // 0) fp32 -> fp16 operand conversions
    cvt_f16<<<4096, 256, 0, stream>>>(hidden, hidden16, 1048576);
    cvt_f16<<<3072, 256, 0, stream>>>(w_qkv, wqkv16, 786432);
    cvt_f16<<<2048, 256, 0, stream>>>(w_dense, wdense16, 524288);

    // 1) QKV projection (fp16 MFMA GEMM, f16 out)
    gemm_f16<true><<<dim3(QKVN / 128, (B_ * S_) / 128), 256, 0, stream>>>(
        hidden16, wqkv16, qkv16, B_ * S_, QKVN, HID_);

    // 2) RMSNorm + RoPE; Q fp32, K split-bf16  (wave-per-row, no barriers)
    norm_rope<<<dim3(5, S_, B_), 256, 0, stream>>>(
        qkv16, cosT, sinT, q_ln, k_ln, Q, Khi, Klo);

    // 3) V transpose -> bf16 (B*HK, D, S)
    vtrans<<<dim3(S_ / 64, B_ * HK_), 256, 0, stream>>>(qkv16, Vt);

    // 4) MFMA flash attention -> attn16 (B,S,H*D) fp16
    flash_mfma<<<dim3(S_ / 128, H_, B_), 256, 0, stream>>>(Q, Khi, Klo, Vt, attn16);

    // 5) dense projection (fp16 MFMA GEMM, fp32 out)
    gemm_f16<false><<<dim3(HID_ / 128, (B_ * S_) / 128), 256, 0, stream>>>(
        attn16, wdense16, out, B_ * S_, HID_, H_ * D_);
}

// Round 2
// 341.467 us; speedup vs baseline: 1.2583x; 1.2110x over previous
//
#include <hip/hip_runtime.h>
#include <hip/hip_bf16.h>
#include <math.h>

#define B_   2
#define S_   2048
#define HID_ 2048
#define H_   16
#define HK_  4
#define D_   128
#define NH_  24          // H + 2*HK
#define QKVN 3072        // NH_ * D_
#define R_   64

typedef __attribute__((ext_vector_type(8))) short sh8;       // 8 bf16
typedef __attribute__((ext_vector_type(2))) short sh2;
typedef __attribute__((ext_vector_type(8))) _Float16 h8;     // 8 fp16 MFMA frag
typedef __attribute__((ext_vector_type(4))) _Float16 h4;     // 4 fp16 (b64)
typedef __attribute__((ext_vector_type(2))) _Float16 h2;
typedef __attribute__((ext_vector_type(4))) float f4;        // MFMA accumulator

// async global->LDS, 16B per lane; LDS dest = wave-uniform base + lane*16
#define GLOAD16(gp, lp) __builtin_amdgcn_global_load_lds(                      \
    (const __attribute__((address_space(1))) void*)(gp),                       \
    (__attribute__((address_space(3))) void*)(lp), 16, 0, 0)

// ---------------------------------------------------------------------------
// fp32 -> fp16 conversion, 8 elems/thread. n8 = n/8.
// ---------------------------------------------------------------------------
__global__ __launch_bounds__(256) void cvt_f16(
    const float* __restrict__ src, _Float16* __restrict__ dst, int n8)
{
    int i = blockIdx.x * 256 + threadIdx.x;
    if (i < n8) {
        float4 a = ((const float4*)src)[i * 2];
        float4 b = ((const float4*)src)[i * 2 + 1];
        h8 h;
        h[0] = (_Float16)a.x; h[1] = (_Float16)a.y;
        h[2] = (_Float16)a.z; h[3] = (_Float16)a.w;
        h[4] = (_Float16)b.x; h[5] = (_Float16)b.y;
        h[6] = (_Float16)b.z; h[7] = (_Float16)b.w;
        ((h8*)dst)[i] = h;
    }
}

// ---------------------------------------------------------------------------
// fp16 MFMA GEMM: C[M][N] = A[M][K] * B[N][K]^T, fp32 accumulate.
// 128x128 tile, BK=64, 4 waves (2x2), wave tile 64x64.
// global_load_lds width=16 staging, both-sides XOR chunk swizzle.
// ---------------------------------------------------------------------------
template<bool F16OUT>
__global__ __launch_bounds__(256) void gemm_f16(
    const _Float16* __restrict__ A, const _Float16* __restrict__ Bm,
    void* __restrict__ Cv, int M, int N, int K)
{
    __shared__ _Float16 Ast[128][64];   // linear: global_load_lds dest
    __shared__ _Float16 Bst[128][64];

    const int tid = threadIdx.x;
    const int wave = tid >> 6, lane = tid & 63;
    const int l15 = lane & 15, l4 = lane >> 4;
    const int m0 = blockIdx.y * 128, n0 = blockIdx.x * 128;
    const int wm = (wave >> 1) * 64, wn = (wave & 1) * 64;

    f4 acc[16];
#pragma unroll
    for (int t = 0; t < 16; ++t) acc[t] = (f4){0.f, 0.f, 0.f, 0.f};

    const int srow = lane >> 3;                    // row within 8-row chunk
    const int scol = ((lane & 7) ^ srow) * 8;      // inverse-swizzled source col
    const int sw   = l15 & 7;                      // read-side row swizzle key

    for (int k0 = 0; k0 < K; k0 += 64) {
        __syncthreads();   // prev iter's ds_reads drained
#pragma unroll
        for (int t = 0; t < 4; ++t) {
            const int chunk = wave * 4 + t;        // 0..15: 8 rows each
            const int grow  = chunk * 8 + srow;
            GLOAD16(A  + (size_t)(m0 + grow) * K + k0 + scol, &Ast[chunk * 8][0]);
            GLOAD16(Bm + (size_t)(n0 + grow) * K + k0 + scol, &Bst[chunk * 8][0]);
        }
        __syncthreads();   // vmcnt(0) drain: LDS tile ready

#pragma unroll
        for (int j = 0; j < 2; ++j) {
            h8 ahf[4], bhf[4];
#pragma unroll
            for (int i = 0; i < 4; ++i) {
                ahf[i] = *(const h8*)&Ast[wm + i * 16 + l15][((j * 4 + l4) ^ sw) * 8];
                bhf[i] = *(const h8*)&Bst[wn + i * 16 + l15][((j * 4 + l4) ^ sw) * 8];
            }
            __builtin_amdgcn_s_setprio(1);
#pragma unroll
            for (int i = 0; i < 4; ++i)
#pragma unroll
                for (int jj = 0; jj < 4; ++jj)
                    acc[i * 4 + jj] = __builtin_amdgcn_mfma_f32_16x16x32_f16(
                        ahf[i], bhf[jj], acc[i * 4 + jj], 0, 0, 0);
            __builtin_amdgcn_s_setprio(0);
        }
    }

#pragma unroll
    for (int i = 0; i < 4; ++i)
#pragma unroll
        for (int jj = 0; jj < 4; ++jj)
#pragma unroll
            for (int r = 0; r < 4; ++r) {
                int row = m0 + wm + i * 16 + l4 * 4 + r;
                int col = n0 + wn + jj * 16 + l15;
                if (F16OUT)
                    ((_Float16*)Cv)[(size_t)row * N + col] = (_Float16)acc[i * 4 + jj][r];
                else
                    ((float*)Cv)[(size_t)row * N + col] = acc[i * 4 + jj][r];
            }
}

// ---------------------------------------------------------------------------
// Fused RMSNorm (q,k heads) + partial RoPE, one wave per head-row.
//   h in [0,16)  -> Qh fp16 (B,H,S,D), PRE-SCALED by 1/sqrt(128)*log2(e)
//   h in [16,20) -> Kh fp16 (B,HK,S,D)
// ---------------------------------------------------------------------------
__global__ __launch_bounds__(256) void norm_rope(
    const _Float16* __restrict__ qkv,
    const float* __restrict__ cosT, const float* __restrict__ sinT,
    const float* __restrict__ qw, const float* __restrict__ kw,
    _Float16* __restrict__ Qh_g, _Float16* __restrict__ Kh_g)
{
    const int tid = threadIdx.x;
    const int wave = tid >> 6, lane = tid & 63;
    const int h = blockIdx.x * 4 + wave;    // 0..19
    const int s = blockIdx.y, b = blockIdx.z;
    const size_t tok = (size_t)b * S_ + s;

    h2 xv = *(const h2*)(qkv + (tok * NH_ + h) * D_ + 2 * lane);
    float x0 = (float)xv[0], x1 = (float)xv[1];
    float ss = x0 * x0 + x1 * x1;
    ss += __shfl_xor(ss, 1);  ss += __shfl_xor(ss, 2);  ss += __shfl_xor(ss, 4);
    ss += __shfl_xor(ss, 8);  ss += __shfl_xor(ss, 16); ss += __shfl_xor(ss, 32);
    float scale = rsqrtf(ss * (1.f / 128.f) + 1e-6f);

    const float* wp = (h < 16) ? qw : kw;
    float2 wv = ((const float2*)wp)[lane];
    float y0 = x0 * scale * wv.x;
    float y1 = x1 * scale * wv.y;

    // RoPE: d<32 -> other = -y[d+32]; 32<=d<64 -> other = +y[d-32]; d>=64 pass
    float p0 = __shfl_xor(y0, 16), p1 = __shfl_xor(y1, 16);
    if (lane < 32) {
        float2 cv = ((const float2*)(cosT + tok * R_))[lane];
        float2 sv = ((const float2*)(sinT + tok * R_))[lane];
        float sgn = (lane < 16) ? -1.f : 1.f;
        y0 = y0 * cv.x + sgn * p0 * sv.x;
        y1 = y1 * cv.y + sgn * p1 * sv.y;
    }

    if (h < 16) {
        const float QS = 0.08838834764831845f * 1.4426950408889634f;
        h2 o; o[0] = (_Float16)(y0 * QS); o[1] = (_Float16)(y1 * QS);
        *(h2*)(Qh_g + (((size_t)b * H_ + h) * S_ + s) * D_ + 2 * lane) = o;
    } else {
        h2 o; o[0] = (_Float16)y0; o[1] = (_Float16)y1;
        *(h2*)(Kh_g + (((size_t)b * HK_ + (h - 16)) * S_ + s) * D_ + 2 * lane) = o;
    }
}

// ---------------------------------------------------------------------------
// V transpose: reads V heads out of fp16 qkv, writes fp16 Vt (B*HK, D, S).
// ---------------------------------------------------------------------------
__global__ __launch_bounds__(256) void vtrans(
    const _Float16* __restrict__ qkv, _Float16* __restrict__ Vt_g)
{
    __shared__ float Ts[64][132];
    const int tid = threadIdx.x;
    const int sb = blockIdx.x;
    const int bh = blockIdx.y;
    const int b = bh >> 2, kh = bh & 3;

#pragma unroll
    for (int t = 0; t < 4; ++t) {
        int e = (tid + 256 * t) * 8;
        int s = e >> 7, d = e & 127;
        const _Float16* p = qkv + (((size_t)(b * S_ + sb * 64 + s)) * NH_ + 20 + kh) * D_ + d;
        h8 v = *(const h8*)p;
#pragma unroll
        for (int u = 0; u < 8; ++u) Ts[s][d + u] = (float)v[u];
    }
    __syncthreads();

#pragma unroll
    for (int tt = 0; tt < 2; ++tt) {
        int dr = (tid >> 2) + 64 * tt;
        int sc = (tid & 3) * 16;
        _Float16 tmp[16];
#pragma unroll
        for (int i = 0; i < 16; ++i) tmp[i] = (_Float16)Ts[sc + i][dr];
        _Float16* outp = Vt_g + ((size_t)bh * D_ + dr) * S_ + sb * 64 + sc;
        *(h8*)outp       = *(h8*)&tmp[0];
        *(h8*)(outp + 8) = *(h8*)&tmp[8];
    }
}

// ---------------------------------------------------------------------------
// MFMA flash attention, all-fp16 operands, fixed-shift softmax.
// Scores bounded: |q.k|/sqrt(128) <= sqrt(128), so exp2 arg in [-16.3, 16.3];
// subtract 8 -> P = exp2(s-8) <= 2^8.3, safely inside fp16 range; the shift
// cancels in the softmax denominator.
// Q-tile 128, KV-tile 64, 4 waves. QK^T SWAPPED (mfma(K,Q)): lane's 4 acc
// values = 4 consecutive kv of one q-row -> b64 P-store.
// LDS: unpadded K[64][128] / V[128][64] / P[128][64], 16B-granule XOR swizzle
// (granule ^= row&7). K/V staged via global_load_lds (linear LDS dest,
// inverse-swizzled GLOBAL source); all reads apply the same involution.
// LDS 48 KB. No setprio (lockstep waves: m190).
// ---------------------------------------------------------------------------
__global__ __launch_bounds__(256, 2) void flash_mfma(
    const _Float16* __restrict__ Qh_g, const _Float16* __restrict__ Kh_g,
    const _Float16* __restrict__ Vt_g, _Float16* __restrict__ Ao)
{
    __shared__ _Float16 Ksh[64][128];   // [kv][d], granule-swizzled
    __shared__ _Float16 Vsh[128][64];   // [d][kv], granule-swizzled
    __shared__ _Float16 Ps [128][64];   // [q][kv],  granule-swizzled

    const int tid = threadIdx.x;
    const int wave = tid >> 6, lane = tid & 63;
    const int l15 = lane & 15, l4 = lane >> 4;
    const int qb = blockIdx.x, h = blockIdx.y, b = blockIdx.z;
    const int kh = h >> 2;
    const int key = l15 & 7;            // read-side swizzle key (row&7)

    // ---- Q fragments: direct fp16 loads (pre-scaled in norm_rope) ----
    h8 qf[2][4];
#pragma unroll
    for (int i = 0; i < 2; ++i) {
        const _Float16* qrow = Qh_g +
            (((size_t)b * H_ + h) * S_ + qb * 128 + wave * 32 + i * 16 + l15) * D_;
#pragma unroll
        for (int j = 0; j < 4; ++j)
            qf[i][j] = *(const h8*)(qrow + j * 32 + l4 * 8);
    }

    f4 o[2][8];
#pragma unroll
    for (int i = 0; i < 2; ++i)
#pragma unroll
        for (int t = 0; t < 8; ++t) o[i][t] = (f4){0.f, 0.f, 0.f, 0.f};
    float l_part[2] = {0.f, 0.f};

    const size_t kvoff = ((size_t)b * HK_ + kh) * S_ * D_;
    const _Float16* kg = Kh_g + kvoff;   // (S, D)
    const _Float16* vg = Vt_g + kvoff;   // (D, S)

    // staging geometry (per wave: K rows w*16..+15, V rows w*32..+31)
    int krow[4], ksrc[4], vrow[4], vsrc[4];
#pragma unroll
    for (int t = 0; t < 4; ++t) {
        krow[t] = wave * 16 + t * 4 + (lane >> 4);            // kv row 0..63
        ksrc[t] = ((lane & 15) ^ (krow[t] & 7)) * 8;          // inv-swz col (halfs)
        vrow[t] = wave * 32 + t * 8 + (lane >> 3);            // d row 0..127
        vsrc[t] = ((lane & 7) ^ (vrow[t] & 7)) * 8;           // inv-swz col (halfs)
    }

    for (int kb = 0; kb < S_ / 64; ++kb) {
        __syncthreads();   // all waves done reading prev tile
#pragma unroll
        for (int t = 0; t < 4; ++t)
            GLOAD16(kg + (size_t)(kb * 64 + krow[t]) * D_ + ksrc[t],
                    &Ksh[wave * 16 + t * 4][0]);
#pragma unroll
        for (int t = 0; t < 4; ++t)
            GLOAD16(vg + (size_t)vrow[t] * S_ + kb * 64 + vsrc[t],
                    &Vsh[wave * 32 + t * 8][0]);
        __syncthreads();   // vmcnt(0) drain: K/V tile ready

        // ---- QK^T swapped: acc[c][i] -> q = l15 (+i*16), kv = c*16+l4*4+r ----
        f4 acc[4][2];
#pragma unroll
        for (int c = 0; c < 4; ++c)
#pragma unroll
            for (int i = 0; i < 2; ++i) acc[c][i] = (f4){0.f, 0.f, 0.f, 0.f};
#pragma unroll
        for (int j = 0; j < 4; ++j) {
#pragma unroll
            for (int c = 0; c < 4; ++c) {
                h8 kf = *(const h8*)&Ksh[c * 16 + l15][((j * 4 + l4) ^ key) * 8];
#pragma unroll
                for (int i = 0; i < 2; ++i)
                    acc[c][i] = __builtin_amdgcn_mfma_f32_16x16x32_f16(
                        kf, qf[i][j], acc[c][i], 0, 0, 0);
            }
        }

        // ---- exp2(s-8) + swizzled b64 P-store (rows wave-local, no barrier) ----
#pragma unroll
        for (int c = 0; c < 4; ++c) {
#pragma unroll
            for (int i = 0; i < 2; ++i) {
                h4 pk;
#pragma unroll
                for (int r = 0; r < 4; ++r) {
                    float e_ = exp2f(acc[c][i][r] - 8.f);
                    l_part[i] += e_;
                    pk[r] = (_Float16)e_;
                }
                int g = 2 * c + (l4 >> 1);                    // 16B granule
                *(h4*)&Ps[wave * 32 + i * 16 + l15][(g ^ key) * 8 + (l4 & 1) * 4] = pk;
            }
        }

        // ---- PV ----
#pragma unroll
        for (int s2 = 0; s2 < 2; ++s2) {
            int gc = ((s2 * 4 + l4) ^ key) * 8;
            h8 pf0 = *(const h8*)&Ps[wave * 32 + l15][gc];
            h8 pf1 = *(const h8*)&Ps[wave * 32 + 16 + l15][gc];
#pragma unroll
            for (int t = 0; t < 8; ++t) {
                h8 vf = *(const h8*)&Vsh[t * 16 + l15][gc];
                o[0][t] = __builtin_amdgcn_mfma_f32_16x16x32_f16(pf0, vf, o[0][t], 0, 0, 0);
                o[1][t] = __builtin_amdgcn_mfma_f32_16x16x32_f16(pf1, vf, o[1][t], 0, 0, 0);
            }
        }
    }

    // ---- softmax denominator (q = i*16 + l15), broadcast to C-layout rows ----
    float Linv[2];
#pragma unroll
    for (int i = 0; i < 2; ++i) {
        float l = l_part[i];
        l += __shfl_xor(l, 16);
        l += __shfl_xor(l, 32);
        Linv[i] = 1.f / l;
    }
#pragma unroll
    for (int i = 0; i < 2; ++i) {
        float inv[4];
#pragma unroll
        for (int r = 0; r < 4; ++r) inv[r] = __shfl(Linv[i], l4 * 4 + r);
#pragma unroll
        for (int t = 0; t < 8; ++t) {
#pragma unroll
            for (int r = 0; r < 4; ++r) {
                int row = qb * 128 + wave * 32 + i * 16 + l4 * 4 + r;
                Ao[((size_t)b * S_ + row) * (H_ * D_) + h * D_ + t * 16 + l15] =
                    (_Float16)(o[i][t][r] * inv[r]);
            }
        }
    }
}

// ---------------------------------------------------------------------------
extern "C" void kernel_launch(void* const* d_in, const int* in_sizes, int n_in,
                              void* d_out, int out_size, void* d_ws, size_t ws_size,
                              hipStream_t stream)
{
    const float* hidden  = (const float*)d_in[0];
    const float* cosT    = (const float*)d_in[1];
    const float* sinT    = (const float*)d_in[2];
    const float* w_qkv   = (const float*)d_in[3];
    const float* q_ln    = (const float*)d_in[4];
    const float* k_ln    = (const float*)d_in[5];
    const float* w_dense = (const float*)d_in[6];
    float* out = (float*)d_out;

    // workspace layout (bytes):
    //   qkv16    : B*S*3072 f16     = 25,165,824   [attn16 aliases]
    //   Qh       : B*H*S*D f16      = 16,777,216   [hidden16 (16MB) aliases]
    //   Kh       : B*HK*S*D f16     =  4,194,304 \
    //   Vt       : B*HK*S*D f16     =  4,194,304  | wqkv16 (12.6MB) aliases
    //   spare    :                     4,194,304 /
    //   wdense16 : 2048*2048 f16    =  8,388,608
    // total 62.9 MB
    char* w = (char*)d_ws;
    _Float16* qkv16 = (_Float16*)w;
    _Float16* Qh    = (_Float16*)(w + 25165824);
    _Float16* Kh    = (_Float16*)(w + 41943040);
    _Float16* Vt    = (_Float16*)(w + 46137344);
    _Float16* wdense16 = (_Float16*)(w + 54525952);
    _Float16* hidden16 = Qh;                 // dead before norm_rope writes Qh
    _Float16* wqkv16   = Kh;                 // dead before norm_rope writes Kh
    _Float16* attn16   = qkv16;              // qkv16 dead after vtrans

    // 0) fp32 -> fp16 operand conversions
    cvt_f16<<<4096, 256, 0, stream>>>(hidden, hidden16, 1048576);
    cvt_f16<<<3072, 256, 0, stream>>>(w_qkv, wqkv16, 786432);
    cvt_f16<<<2048, 256, 0, stream>>>(w_dense, wdense16, 524288);

    // 1) QKV projection (fp16 MFMA GEMM, f16 out)
    gemm_f16<true><<<dim3(QKVN / 128, (B_ * S_) / 128), 256, 0, stream>>>(
        hidden16, wqkv16, qkv16, B_ * S_, QKVN, HID_);

    // 2) RMSNorm + RoPE; Qh fp16 pre-scaled, Kh fp16
    norm_rope<<<dim3(5, S_, B_), 256, 0, stream>>>(
        qkv16, cosT, sinT, q_ln, k_ln, Qh, Kh);

    // 3) V transpose -> fp16 (B*HK, D, S)
    vtrans<<<dim3(S_ / 64, B_ * HK_), 256, 0, stream>>>(qkv16, Vt);

    // 4) MFMA flash attention -> attn16 (B,S,H*D) fp16
    flash_mfma<<<dim3(S_ / 128, H_, B_), 256, 0, stream>>>(Qh, Kh, Vt, attn16);

    // 5) dense projection (fp16 MFMA GEMM, fp32 out)
    gemm_f16<false><<<dim3(HID_ / 128, (B_ * S_) / 128), 256, 0, stream>>>(
        attn16, wdense16, out, B_ * S_, HID_, H_ * D_);
}